// Round 2
// baseline (427.857 us; speedup 1.0000x reference)
//
#include <hip/hip_runtime.h>
#include <math.h>

// Kernel 1: compute the 4x4 transform (row-major) into workspace.
// trans = [[ scale_col(delta_r @ R) | T + Vm@rho ],
//          [ 0 0 0 1 ]]
__global__ void build_trans(const float* __restrict__ rot_delta,
                            const float* __restrict__ trans_delta,
                            const float* __restrict__ scale,
                            const float* __restrict__ Rin,
                            const float* __restrict__ Tin,
                            float* __restrict__ M) {
    if (threadIdx.x != 0 || blockIdx.x != 0) return;

    const float th0 = rot_delta[0], th1 = rot_delta[1], th2 = rot_delta[2];
    const float r0 = trans_delta[0], r1 = trans_delta[1], r2 = trans_delta[2];

    const float angle = sqrtf(th0*th0 + th1*th1 + th2*th2);
    const bool small = angle < 1e-5f;
    const float a = small ? 1.0f : angle;
    const float s = sinf(a), c = cosf(a);
    const float A = small ? 1.0f        : s / a;
    const float B = small ? 0.5f        : (1.0f - c) / (a * a);
    const float C = small ? (1.0f/6.0f) : (a - s) / (a * a * a);

    // W = skew(theta)
    float W[3][3] = {{0.0f, -th2,  th1},
                     { th2, 0.0f, -th0},
                     {-th1,  th0, 0.0f}};
    float W2[3][3];
    for (int i = 0; i < 3; ++i)
        for (int j = 0; j < 3; ++j)
            W2[i][j] = W[i][0]*W[0][j] + W[i][1]*W[1][j] + W[i][2]*W[2][j];

    float Rd[3][3], Vm[3][3];
    for (int i = 0; i < 3; ++i)
        for (int j = 0; j < 3; ++j) {
            const float I = (i == j) ? 1.0f : 0.0f;
            Rd[i][j] = I + A * W[i][j] + B * W2[i][j];
            Vm[i][j] = I + B * W[i][j] + C * W2[i][j];
        }

    // delta_t = Vm @ rho
    const float dt0 = Vm[0][0]*r0 + Vm[0][1]*r1 + Vm[0][2]*r2;
    const float dt1 = Vm[1][0]*r0 + Vm[1][1]*r1 + Vm[1][2]*r2;
    const float dt2 = Vm[2][0]*r0 + Vm[2][1]*r1 + Vm[2][2]*r2;

    // S = delta_r @ R, then column j scaled by scale[j]
    for (int i = 0; i < 3; ++i)
        for (int j = 0; j < 3; ++j) {
            const float v = Rd[i][0]*Rin[0*3+j] + Rd[i][1]*Rin[1*3+j] + Rd[i][2]*Rin[2*3+j];
            M[i*4 + j] = scale[j] * v;
        }
    M[0*4 + 3] = Tin[0] + dt0;
    M[1*4 + 3] = Tin[1] + dt1;
    M[2*4 + 3] = Tin[2] + dt2;
    M[3*4 + 0] = 0.0f; M[3*4 + 1] = 0.0f; M[3*4 + 2] = 0.0f; M[3*4 + 3] = 1.0f;
}

// Kernel 2: out[i] = trans @ x[i]  (out[i][j] = dot(trans row j, x[i])).
// Row 3 of trans is [0,0,0,1] -> out.w = x.w.
__global__ __launch_bounds__(256) void apply_trans(const float4* __restrict__ x,
                                                   const float* __restrict__ M,
                                                   float4* __restrict__ out,
                                                   int n) {
    // Uniform loads -> SGPRs, live across the whole kernel.
    const float m00 = M[0],  m01 = M[1],  m02 = M[2],  m03 = M[3];
    const float m10 = M[4],  m11 = M[5],  m12 = M[6],  m13 = M[7];
    const float m20 = M[8],  m21 = M[9],  m22 = M[10], m23 = M[11];

    const int i = blockIdx.x * blockDim.x + threadIdx.x;
    if (i >= n) return;
    const float4 v = x[i];
    float4 o;
    o.x = fmaf(m00, v.x, fmaf(m01, v.y, fmaf(m02, v.z, m03 * v.w)));
    o.y = fmaf(m10, v.x, fmaf(m11, v.y, fmaf(m12, v.z, m13 * v.w)));
    o.z = fmaf(m20, v.x, fmaf(m21, v.y, fmaf(m22, v.z, m23 * v.w)));
    o.w = v.w;
    out[i] = o;
}

extern "C" void kernel_launch(void* const* d_in, const int* in_sizes, int n_in,
                              void* d_out, int out_size, void* d_ws, size_t ws_size,
                              hipStream_t stream) {
    const float* x          = (const float*)d_in[0];
    const float* rot_delta  = (const float*)d_in[1];
    const float* trans_delta= (const float*)d_in[2];
    const float* scale      = (const float*)d_in[3];
    const float* R          = (const float*)d_in[4];
    const float* T          = (const float*)d_in[5];
    float* M = (float*)d_ws;               // 16 floats of scratch

    build_trans<<<1, 64, 0, stream>>>(rot_delta, trans_delta, scale, R, T, M);

    const int n = in_sizes[0] / 4;         // number of float4 points
    const int block = 256;
    const int grid = (n + block - 1) / block;
    apply_trans<<<grid, block, 0, stream>>>((const float4*)x, M, (float4*)d_out, n);
}